// Round 1
// baseline (282.031 us; speedup 1.0000x reference)
//
#include <hip/hip_runtime.h>

#define D_MODEL 1024
#define D_FF    8192
#define N_ELEM  64
#define D1      128
#define BATCH   2048
#define B_T     8      // batch rows per block (main kernel)
#define NJT     8      // j tiles (== XCD count)
#define JT      16     // j per tile

typedef unsigned short u16;
typedef unsigned int   u32;
typedef _Float16 h2    __attribute__((ext_vector_type(2)));
typedef float    f32x4 __attribute__((ext_vector_type(4)));
typedef u32      u32x2 __attribute__((ext_vector_type(2)));
typedef u32      u32x4 __attribute__((ext_vector_type(4)));

__device__ __forceinline__ h2 as_h2(u32 u) { union { u32 i; h2 h; } c; c.i = u; return c.h; }
__device__ __forceinline__ u32 pkh(float a, float b) {
    union { h2 h; u32 u; } c; c.h.x = (_Float16)a; c.h.y = (_Float16)b; return c.u;
}
__device__ __forceinline__ u16 f2h(float f) {
    union { _Float16 h; u16 u; } c; c.h = (_Float16)f; return c.u;
}
__device__ __forceinline__ f32x4 ntload4(const float* p) {
    return __builtin_nontemporal_load((const f32x4*)p);
}
// 2-way f16 dot with f32 accumulate: v_dot2_f32_f16 (2 MAC/inst)
__device__ __forceinline__ float dot2(u32 a, u32 b, float c) {
#if __has_builtin(__builtin_amdgcn_fdot2)
    return __builtin_amdgcn_fdot2(as_h2(a), as_h2(b), c, false);
#else
    const h2 ha = as_h2(a), hb = as_h2(b);
    c = fmaf((float)ha.x, (float)hb.x, c);
    return fmaf((float)ha.y, (float)hb.y, c);
#endif
}

// ---------------------------------------------------------------------------
// Fused prep: blocks [0,2048) transpose+cast w1 -> w1h [j*64+e][d] f16;
// blocks [2048,6144) cast w2 -> f16. One launch instead of two serialized.
// ---------------------------------------------------------------------------
#define TW1_BLOCKS ((D_FF / 64) * (D_MODEL / 64))   // 2048
__global__ __launch_bounds__(256) void prep_weights(const float* __restrict__ w1,
                                                    u16* __restrict__ w1h,
                                                    const float* __restrict__ w2,
                                                    u16* __restrict__ w2h) {
    __shared__ float tile[64][65];
    if (blockIdx.x < TW1_BLOCKS) {
        const int c0 = (blockIdx.x & (D_FF / 64 - 1)) * 64;
        const int d0 = (blockIdx.x >> 7) * 64;          // D_FF/64 == 128
        const int tx = threadIdx.x & 15;
        const int ty = threadIdx.x >> 4;
#pragma unroll
        for (int r = 0; r < 4; ++r) {
            const int row = ty * 4 + r;
            const float4 v = *(const float4*)(w1 + (size_t)(d0 + row) * D_FF + c0 + tx * 4);
            tile[row][tx * 4 + 0] = v.x;
            tile[row][tx * 4 + 1] = v.y;
            tile[row][tx * 4 + 2] = v.z;
            tile[row][tx * 4 + 3] = v.w;
        }
        __syncthreads();
#pragma unroll
        for (int r = 0; r < 4; ++r) {
            const int c = ty * 4 + r;
            ushort4 o;
            o.x = f2h(tile[tx * 4 + 0][c]);
            o.y = f2h(tile[tx * 4 + 1][c]);
            o.z = f2h(tile[tx * 4 + 2][c]);
            o.w = f2h(tile[tx * 4 + 3][c]);
            *(ushort4*)(w1h + (size_t)(c0 + c) * D_MODEL + d0 + tx * 4) = o;
        }
    } else {
        const size_t i = ((size_t)(blockIdx.x - TW1_BLOCKS) * 256 + threadIdx.x) * 8;
        const float4 a = *(const float4*)(w2 + i);
        const float4 b = *(const float4*)(w2 + i + 4);
        ushort4 oa, ob;
        oa.x = f2h(a.x); oa.y = f2h(a.y); oa.z = f2h(a.z); oa.w = f2h(a.w);
        ob.x = f2h(b.x); ob.y = f2h(b.y); ob.z = f2h(b.z); ob.w = f2h(b.w);
        *(ushort4*)(w2h + i)     = oa;
        *(ushort4*)(w2h + i + 4) = ob;
    }
}

// ---------------------------------------------------------------------------
// Main. Same decomposition as proven r5/r9 skeleton (XCD-affine j tiles,
// FETCH 51 MB). Rework of the latency-bound inner structure:
//   phase 1: quarter-wave (16 lanes) owns one j. Lane reads 16B chunks of
//     the gathered w1h row (256B contiguous per quarter, 4 loads in flight,
//     imm offsets off one base), x fragments ds_read once per half-row and
//     broadcast across quarters (same addr -> free). v_dot2_f32_f16 = 2
//     MAC/inst. Reduce: 4 shfl levels within 16 lanes (was 6 levels x 2
//     vals over 64 lanes -> 192 shuffles/wave, now 32).
//   phase 2: wave-pair split (waves 0-1 vs 2-3) = 2 batch rows at a time,
//     16B w2h loads (was 8B), relu/mask rows preloaded to registers,
//     readfirstlane scalarizes the row base (wave-uniform). Branch on
//     relu==0 stays wave-uniform.
// ---------------------------------------------------------------------------
__global__ __launch_bounds__(256, 6) void sparse_ff_jt(const int* __restrict__ mask,
                                                       const float* __restrict__ x,
                                                       const u16* __restrict__ w1h_,
                                                       const u16* __restrict__ w2h_,
                                                       u16* __restrict__ part) {
    const _Float16* w1h = (const _Float16*)w1h_;
    const _Float16* w2h = (const _Float16*)w2h_;
    __shared__ u16   x_lds[B_T][D_MODEL];   // f16, 16 KB
    __shared__ float r_lds[B_T][JT];
    __shared__ int   m_lds[B_T][JT];

    const int jt = blockIdx.x & (NJT - 1);          // XCD-affine j tile
    const int b0 = (blockIdx.x >> 3) * B_T;
    const int t = threadIdx.x;
    const int wave = t >> 6;
    const int lane = t & 63;
    const int q = lane >> 4;        // quarter 0..3 -> which j of the group
    const int l = lane & 15;        // lane within quarter

    // stage x rows (f32 nt coalesced -> f16 LDS) + mask row, one barrier
#pragma unroll
    for (int r = 0; r < B_T; ++r) {
        const f32x4 v = ntload4(x + (size_t)(b0 + r) * D_MODEL + t * 4);
        u32x2 o; o.x = pkh(v.x, v.y); o.y = pkh(v.z, v.w);
        *(u32x2*)&x_lds[r][t * 4] = o;
    }
    if (t < B_T * JT) {
        m_lds[t >> 4][t & 15] = mask[(b0 + (t >> 4)) * D1 + jt * JT + (t & 15)];
    }
    __syncthreads();

    // ---- phase 1: wave does 2 batch rows; quarter q owns j = q*4+jg ----
#pragma unroll
    for (int rep = 0; rep < 2; ++rep) {
        const int bi = wave * 2 + rep;
        const int4 mv = *(const int4*)&m_lds[bi][q * 4];
        const int mj[4] = {mv.x, mv.y, mv.z, mv.w};
        float sj[4] = {0.f, 0.f, 0.f, 0.f};
#pragma unroll
        for (int half = 0; half < 2; ++half) {
            // x fragments: 4 x 16B, identical addr across quarters (broadcast)
            uint4 xv[4];
#pragma unroll
            for (int i = 0; i < 4; ++i)
                xv[i] = *(const uint4*)&x_lds[bi][half * 512 + i * 128 + l * 8];
#pragma unroll
            for (int jg = 0; jg < 4; ++jg) {
                const int j0 = jt * JT + q * 4 + jg;
                const _Float16* row =
                    w1h + (size_t)((j0 << 6) + mj[jg]) * D_MODEL + half * 512 + l * 8;
                uint4 wv[4];
#pragma unroll
                for (int i = 0; i < 4; ++i)
                    wv[i] = *(const uint4*)(row + i * 128);   // imm offset i*256B
#pragma unroll
                for (int i = 0; i < 4; ++i) {
                    sj[jg] = dot2(wv[i].x, xv[i].x, sj[jg]);
                    sj[jg] = dot2(wv[i].y, xv[i].y, sj[jg]);
                    sj[jg] = dot2(wv[i].z, xv[i].z, sj[jg]);
                    sj[jg] = dot2(wv[i].w, xv[i].w, sj[jg]);
                }
            }
        }
        // reduce within quarter: 4 levels over 16 lanes
#pragma unroll
        for (int jg = 0; jg < 4; ++jg) {
            float s = sj[jg];
            s += __shfl_down(s, 8, 16);
            s += __shfl_down(s, 4, 16);
            s += __shfl_down(s, 2, 16);
            s += __shfl_down(s, 1, 16);
            if (l == 0) r_lds[bi][q * 4 + jg] = fmaxf(s, 0.f);
        }
    }
    __syncthreads();

    // ---- phase 2: wave-pair handles 2 bi at a time, 8 dims/thread ----
    const int halfsel = t >> 7;            // waves 0-1 -> 0, waves 2-3 -> 1
    const int d0q = (t & 127) * 8;
#pragma unroll
    for (int p = 0; p < 4; ++p) {
        const int bi = p * 2 + halfsel;
        float rr[16];
        int   mm[16];
#pragma unroll
        for (int i = 0; i < 4; ++i) {
            *(float4*)&rr[i * 4] = *(const float4*)&r_lds[bi][i * 4];
            *(int4*)&mm[i * 4]   = *(const int4*)&m_lds[bi][i * 4];
        }
        float a[8] = {0.f, 0.f, 0.f, 0.f, 0.f, 0.f, 0.f, 0.f};
#pragma unroll
        for (int jj = 0; jj < JT; ++jj) {
            const float r = rr[jj];
            if (r > 0.f) {                           // wave-uniform branch
                const int m = __builtin_amdgcn_readfirstlane(mm[jj]);
                const _Float16* row =
                    w2h + (size_t)(m * D1 + jt * JT + jj) * D_MODEL + d0q;
                const uint4 v = *(const uint4*)row;
                const h2 p0 = as_h2(v.x), p1 = as_h2(v.y);
                const h2 p2 = as_h2(v.z), p3 = as_h2(v.w);
                a[0] = fmaf(r, (float)p0.x, a[0]); a[1] = fmaf(r, (float)p0.y, a[1]);
                a[2] = fmaf(r, (float)p1.x, a[2]); a[3] = fmaf(r, (float)p1.y, a[3]);
                a[4] = fmaf(r, (float)p2.x, a[4]); a[5] = fmaf(r, (float)p2.y, a[5]);
                a[6] = fmaf(r, (float)p3.x, a[6]); a[7] = fmaf(r, (float)p3.y, a[7]);
            }
        }
        u32x4 o;
        o.x = pkh(a[0], a[1]); o.y = pkh(a[2], a[3]);
        o.z = pkh(a[4], a[5]); o.w = pkh(a[6], a[7]);
        u16* pp = part + ((size_t)jt * BATCH + (b0 + bi)) * D_MODEL + d0q;
        __builtin_nontemporal_store(o, (u32x4*)pp);
    }
}

// ---------------------------------------------------------------------------
// Reduce: res[b] = b2 + sum_jt part[jt][b] (f16 partials); mask echo chunk 0
// ---------------------------------------------------------------------------
__global__ __launch_bounds__(256) void reduce_partials(const int* __restrict__ mask,
                                                       const float* __restrict__ b2,
                                                       const u16* __restrict__ part,
                                                       float* __restrict__ out) {
    const int b = blockIdx.x;
    const int t = threadIdx.x;
    if (t < D1) out[(size_t)b * D1 + t] = (float)mask[b * D1 + t];

    const int d0 = t * 4;
    const float4 bv = *(const float4*)(b2 + d0);
    float a0 = bv.x, a1 = bv.y, a2 = bv.z, a3 = bv.w;
#pragma unroll
    for (int jt = 0; jt < NJT; ++jt) {
        const uint2 v = *(const uint2*)(part + ((size_t)jt * BATCH + b) * D_MODEL + d0);
        const h2 p0 = as_h2(v.x), p1 = as_h2(v.y);
        a0 += (float)p0.x; a1 += (float)p0.y;
        a2 += (float)p1.x; a3 += (float)p1.y;
    }
    *(float4*)(out + (size_t)BATCH * D1 + (size_t)b * D_MODEL + d0) =
        make_float4(a0, a1, a2, a3);
}

// ---------------------------------------------------------------------------
// Fallback (tiny ws): fp32 path, raw strided w1 gather
// ---------------------------------------------------------------------------
__global__ __launch_bounds__(256) void sparse_ff_f32_raw(const int* __restrict__ mask,
                                                         const float* __restrict__ x,
                                                         const float* __restrict__ w1,
                                                         const float* __restrict__ w2,
                                                         const float* __restrict__ b2,
                                                         float* __restrict__ out) {
    __shared__ float x_lds[D_MODEL];
    __shared__ float relu_lds[D1];
    __shared__ int   m_lds[D1];
    const int b = blockIdx.x, t = threadIdx.x;
    const int wave = t >> 6, lane = t & 63;
    *(float4*)&x_lds[t * 4] = *(const float4*)(x + (size_t)b * D_MODEL + t * 4);
    if (t < D1) {
        const int mv = mask[b * D1 + t];
        m_lds[t] = mv;
        out[(size_t)b * D1 + t] = (float)mv;
    }
    __syncthreads();
    for (int jj = 0; jj < 32; ++jj) {
        const int j = wave * 32 + jj;
        const int m = m_lds[j];
        float acc = 0.f;
#pragma unroll
        for (int c = 0; c < 16; ++c) {
            const int d = c * 64 + lane;
            acc = fmaf(w1[(size_t)d * D_FF + j * N_ELEM + m], x_lds[d], acc);
        }
#pragma unroll
        for (int off = 32; off; off >>= 1) acc += __shfl_down(acc, off);
        if (lane == 0) relu_lds[j] = fmaxf(acc, 0.f);
    }
    __syncthreads();
    const int dm0 = t * 4;
    const float4 bv = *(const float4*)(b2 + dm0);
    float a0 = bv.x, a1 = bv.y, a2 = bv.z, a3 = bv.w;
    for (int j = 0; j < D1; ++j) {
        const float r = relu_lds[j];
        if (r > 0.f) {
            const float4 wv = *(const float4*)(w2 + (size_t)(m_lds[j] * D1 + j) * D_MODEL + dm0);
            a0 = fmaf(r, wv.x, a0); a1 = fmaf(r, wv.y, a1);
            a2 = fmaf(r, wv.z, a2); a3 = fmaf(r, wv.w, a3);
        }
    }
    *(float4*)(out + (size_t)BATCH * D1 + (size_t)b * D_MODEL + dm0) =
        make_float4(a0, a1, a2, a3);
}

extern "C" void kernel_launch(void* const* d_in, const int* in_sizes, int n_in,
                              void* d_out, int out_size, void* d_ws, size_t ws_size,
                              hipStream_t stream) {
    const int*   mask = (const int*)d_in[0];
    const float* x    = (const float*)d_in[1];
    const float* w1   = (const float*)d_in[2];
    const float* w2   = (const float*)d_in[3];
    const float* b2   = (const float*)d_in[4];
    float* out = (float*)d_out;

    const size_t w1h_bytes  = (size_t)D_FF * D_MODEL * sizeof(u16);          // 16 MiB
    const size_t w2h_bytes  = (size_t)D_FF * D_MODEL * sizeof(u16);          // 16 MiB
    const size_t part_bytes = (size_t)NJT * BATCH * D_MODEL * sizeof(u16);   // 32 MiB

    if (ws_size >= w1h_bytes + w2h_bytes + part_bytes) {
        u16* w1h  = (u16*)d_ws;
        u16* w2h  = (u16*)((char*)d_ws + w1h_bytes);
        u16* part = (u16*)((char*)d_ws + w1h_bytes + w2h_bytes);
        const int cast_blocks = (D_FF * D_MODEL / 8) / 256;                  // 4096
        prep_weights<<<TW1_BLOCKS + cast_blocks, 256, 0, stream>>>(w1, w1h, w2, w2h);
        sparse_ff_jt<<<(BATCH / B_T) * NJT, 256, 0, stream>>>(mask, x, w1h, w2h, part);
        reduce_partials<<<BATCH, 256, 0, stream>>>(mask, b2, part, out);
    } else {
        sparse_ff_f32_raw<<<BATCH, 256, 0, stream>>>(mask, x, w1, w2, b2, out);
    }
}

// Round 2
// 180.972 us; speedup vs baseline: 1.5584x; 1.5584x over previous
//
#include <hip/hip_runtime.h>

#define D_MODEL 1024
#define D_FF    8192
#define N_ELEM  64
#define D1      128
#define BATCH   2048
#define B_T     8      // batch rows per block (main kernel)
#define NJT     8      // j tiles (== XCD count)
#define JT      16     // j per tile

typedef unsigned short u16;
typedef unsigned int   u32;
typedef _Float16 h2    __attribute__((ext_vector_type(2)));
typedef float    f32x4 __attribute__((ext_vector_type(4)));
typedef u32      u32x2 __attribute__((ext_vector_type(2)));

__device__ __forceinline__ h2 as_h2(u32 u) { union { u32 i; h2 h; } c; c.i = u; return c.h; }
__device__ __forceinline__ u32 pkh(float a, float b) {
    union { h2 h; u32 u; } c; c.h.x = (_Float16)a; c.h.y = (_Float16)b; return c.u;
}
__device__ __forceinline__ u16 f2h(float f) {
    union { _Float16 h; u16 u; } c; c.h = (_Float16)f; return c.u;
}
__device__ __forceinline__ f32x4 ntload4(const float* p) {
    return __builtin_nontemporal_load((const f32x4*)p);
}
// 2-way f16 dot with f32 accumulate: v_dot2_f32_f16 (2 MAC/inst).
// Validated numerically in round 1 (absmax 0.03125, passed).
__device__ __forceinline__ float dot2(u32 a, u32 b, float c) {
#if __has_builtin(__builtin_amdgcn_fdot2)
    return __builtin_amdgcn_fdot2(as_h2(a), as_h2(b), c, false);
#else
    const h2 ha = as_h2(a), hb = as_h2(b);
    c = fmaf((float)ha.x, (float)hb.x, c);
    return fmaf((float)ha.y, (float)hb.y, c);
#endif
}
// dot a uint4 (8 f16) against a uint4 of x fragments
__device__ __forceinline__ float dot8(uint4 w, uint4 q, float c) {
    c = dot2(w.x, q.x, c);
    c = dot2(w.y, q.y, c);
    c = dot2(w.z, q.z, c);
    c = dot2(w.w, q.w, c);
    return c;
}

// ---------------------------------------------------------------------------
// Fused prep: blocks [0,2048) transpose+cast w1 -> w1h [j*64+e][d] f16;
// blocks [2048,6144) cast w2 -> f16. One launch instead of two serialized.
// (Verified correct in round 1.)
// ---------------------------------------------------------------------------
#define TW1_BLOCKS ((D_FF / 64) * (D_MODEL / 64))   // 2048
__global__ __launch_bounds__(256) void prep_weights(const float* __restrict__ w1,
                                                    u16* __restrict__ w1h,
                                                    const float* __restrict__ w2,
                                                    u16* __restrict__ w2h) {
    __shared__ float tile[64][65];
    if (blockIdx.x < TW1_BLOCKS) {
        const int c0 = (blockIdx.x & (D_FF / 64 - 1)) * 64;
        const int d0 = (blockIdx.x >> 7) * 64;          // D_FF/64 == 128
        const int tx = threadIdx.x & 15;
        const int ty = threadIdx.x >> 4;
#pragma unroll
        for (int r = 0; r < 4; ++r) {
            const int row = ty * 4 + r;
            const float4 v = *(const float4*)(w1 + (size_t)(d0 + row) * D_FF + c0 + tx * 4);
            tile[row][tx * 4 + 0] = v.x;
            tile[row][tx * 4 + 1] = v.y;
            tile[row][tx * 4 + 2] = v.z;
            tile[row][tx * 4 + 3] = v.w;
        }
        __syncthreads();
#pragma unroll
        for (int r = 0; r < 4; ++r) {
            const int c = ty * 4 + r;
            ushort4 o;
            o.x = f2h(tile[tx * 4 + 0][c]);
            o.y = f2h(tile[tx * 4 + 1][c]);
            o.z = f2h(tile[tx * 4 + 2][c]);
            o.w = f2h(tile[tx * 4 + 3][c]);
            *(ushort4*)(w1h + (size_t)(c0 + c) * D_MODEL + d0 + tx * 4) = o;
        }
    } else {
        const size_t i = ((size_t)(blockIdx.x - TW1_BLOCKS) * 256 + threadIdx.x) * 8;
        const float4 a = *(const float4*)(w2 + i);
        const float4 b = *(const float4*)(w2 + i + 4);
        ushort4 oa, ob;
        oa.x = f2h(a.x); oa.y = f2h(a.y); oa.z = f2h(a.z); oa.w = f2h(a.w);
        ob.x = f2h(b.x); ob.y = f2h(b.y); ob.z = f2h(b.z); ob.w = f2h(b.w);
        *(ushort4*)(w2h + i)     = oa;
        *(ushort4*)(w2h + i + 4) = ob;
    }
}

// ---------------------------------------------------------------------------
// Main: exact r0 skeleton (proven 64 us / FETCH 51 MB / WRITE 33 MB / occ 70%,
// zero scratch). Round-1's quarter-wave + phase-2 rework spilled ~250 MB of
// scratch each way (symmetric FETCH/WRITE explosion, VALUBusy 8.7%) - reverted.
// Two surgical changes only:
//   (a) explicit 2-deep software pipeline on the jj loop: named uint4 prefetch
//       regs for pair jj+2 issued before computing pair jj. r0's VGPR=28 had
//       exactly one iteration in flight -> ~200cy L2 latency fully exposed.
//   (b) v_dot2_f32_f16 (16 dot2/pair instead of 64 v_fma_mix).
// ---------------------------------------------------------------------------
__global__ __launch_bounds__(256) void sparse_ff_jt(const int* __restrict__ mask,
                                                    const float* __restrict__ x,
                                                    const u16* __restrict__ w1h_,
                                                    const u16* __restrict__ w2h_,
                                                    u16* __restrict__ part) {
    const _Float16* w1h = (const _Float16*)w1h_;
    const _Float16* w2h = (const _Float16*)w2h_;
    __shared__ u16   x_lds[B_T][D_MODEL];   // f16, 16 KB
    __shared__ float r_lds[B_T][JT];
    __shared__ int   m_lds[B_T][JT];

    const int jt = blockIdx.x & (NJT - 1);          // XCD-affine j tile
    const int b0 = (blockIdx.x >> 3) * B_T;
    const int t = threadIdx.x;
    const int wave = t >> 6;
    const int lane = t & 63;

    // stage x rows (f32 nt coalesced -> f16 LDS) + mask row, one barrier
#pragma unroll
    for (int r = 0; r < B_T; ++r) {
        const f32x4 v = ntload4(x + (size_t)(b0 + r) * D_MODEL + t * 4);
        u32x2 o; o.x = pkh(v.x, v.y); o.y = pkh(v.z, v.w);
        *(u32x2*)&x_lds[r][t * 4] = o;
    }
    if (t < B_T * JT) {
        m_lds[t >> 4][t & 15] = mask[(b0 + (t >> 4)) * D1 + jt * JT + (t & 15)];
    }
    __syncthreads();

    // phase 1: wave handles 2 batch rows x 16 j (2-j pairs), 2-deep pipelined
#pragma unroll
    for (int rep = 0; rep < 2; ++rep) {
        const int bi = wave * 2 + rep;
        // loop-invariant x fragments from LDS (16B each, conflict-free)
        const uint4 xA = *(const uint4*)&x_lds[bi][lane * 8];        // elems lane*8..+8
        const uint4 xB = *(const uint4*)&x_lds[bi][512 + lane * 8];  // elems 512+lane*8..+8

        // prologue: loads for pair jj=0
        const _Float16* p0 = w1h + (size_t)(((jt * JT) << 6) + m_lds[bi][0]) * D_MODEL;
        const _Float16* p1 = w1h + (size_t)((((jt * JT) + 1) << 6) + m_lds[bi][1]) * D_MODEL;
        uint4 a0  = *(const uint4*)(p0 + lane * 8);
        uint4 b0v = *(const uint4*)(p0 + 512 + lane * 8);
        uint4 a1  = *(const uint4*)(p1 + lane * 8);
        uint4 b1v = *(const uint4*)(p1 + 512 + lane * 8);

#pragma unroll
        for (int jj = 0; jj < JT; jj += 2) {
            // prefetch pair jj+2 (statically dead on last iteration)
            uint4 na0, nb0, na1, nb1;
            if (jj + 2 < JT) {
                const int j0 = jt * JT + jj + 2;
                const _Float16* c0 = w1h + (size_t)((j0 << 6) + m_lds[bi][jj + 2]) * D_MODEL;
                const _Float16* c1 = w1h + (size_t)(((j0 + 1) << 6) + m_lds[bi][jj + 3]) * D_MODEL;
                na0 = *(const uint4*)(c0 + lane * 8);
                nb0 = *(const uint4*)(c0 + 512 + lane * 8);
                na1 = *(const uint4*)(c1 + lane * 8);
                nb1 = *(const uint4*)(c1 + 512 + lane * 8);
            }

            float s0 = 0.f, s1 = 0.f;
            s0 = dot8(a0, xA, s0);
            s0 = dot8(b0v, xB, s0);
            s1 = dot8(a1, xA, s1);
            s1 = dot8(b1v, xB, s1);

#pragma unroll
            for (int off = 32; off; off >>= 1) {
                s0 += __shfl_down(s0, off);
                s1 += __shfl_down(s1, off);
            }
            if (lane == 0) {
                r_lds[bi][jj]     = fmaxf(s0, 0.f);
                r_lds[bi][jj + 1] = fmaxf(s1, 0.f);
            }
            a0 = na0; b0v = nb0; a1 = na1; b1v = nb1;
        }
    }
    __syncthreads();

    // phase 2: thread owns 4 output dims (r0 exact, proven no-spill)
    const int d0q = t * 4;
    for (int bi = 0; bi < B_T; ++bi) {
        float a0 = 0.f, a1 = 0.f, a2 = 0.f, a3 = 0.f;
        for (int jj = 0; jj < JT; ++jj) {
            const float r = r_lds[bi][jj];
            if (r > 0.f) {                           // workgroup-uniform branch
                const _Float16* row = w2h
                    + (size_t)(m_lds[bi][jj] * D1 + jt * JT + jj) * D_MODEL + d0q;
                const uint2 v = *(const uint2*)row;
                const h2 q0 = as_h2(v.x), q1 = as_h2(v.y);
                a0 = fmaf(r, (float)q0.x, a0); a1 = fmaf(r, (float)q0.y, a1);
                a2 = fmaf(r, (float)q1.x, a2); a3 = fmaf(r, (float)q1.y, a3);
            }
        }
        u32x2 o;
        o.x = pkh(a0, a1);
        o.y = pkh(a2, a3);
        u16* pp = part + ((size_t)jt * BATCH + (b0 + bi)) * D_MODEL + d0q;
        __builtin_nontemporal_store(o, (u32x2*)pp);
    }
}

// ---------------------------------------------------------------------------
// Reduce: res[b] = b2 + sum_jt part[jt][b] (f16 partials); mask echo chunk 0
// ---------------------------------------------------------------------------
__global__ __launch_bounds__(256) void reduce_partials(const int* __restrict__ mask,
                                                       const float* __restrict__ b2,
                                                       const u16* __restrict__ part,
                                                       float* __restrict__ out) {
    const int b = blockIdx.x;
    const int t = threadIdx.x;
    if (t < D1) out[(size_t)b * D1 + t] = (float)mask[b * D1 + t];

    const int d0 = t * 4;
    const float4 bv = *(const float4*)(b2 + d0);
    float a0 = bv.x, a1 = bv.y, a2 = bv.z, a3 = bv.w;
#pragma unroll
    for (int jt = 0; jt < NJT; ++jt) {
        const uint2 v = *(const uint2*)(part + ((size_t)jt * BATCH + b) * D_MODEL + d0);
        const h2 p0 = as_h2(v.x), p1 = as_h2(v.y);
        a0 += (float)p0.x; a1 += (float)p0.y;
        a2 += (float)p1.x; a3 += (float)p1.y;
    }
    *(float4*)(out + (size_t)BATCH * D1 + (size_t)b * D_MODEL + d0) =
        make_float4(a0, a1, a2, a3);
}

// ---------------------------------------------------------------------------
// Fallback (tiny ws): fp32 path, raw strided w1 gather
// ---------------------------------------------------------------------------
__global__ __launch_bounds__(256) void sparse_ff_f32_raw(const int* __restrict__ mask,
                                                         const float* __restrict__ x,
                                                         const float* __restrict__ w1,
                                                         const float* __restrict__ w2,
                                                         const float* __restrict__ b2,
                                                         float* __restrict__ out) {
    __shared__ float x_lds[D_MODEL];
    __shared__ float relu_lds[D1];
    __shared__ int   m_lds[D1];
    const int b = blockIdx.x, t = threadIdx.x;
    const int wave = t >> 6, lane = t & 63;
    *(float4*)&x_lds[t * 4] = *(const float4*)(x + (size_t)b * D_MODEL + t * 4);
    if (t < D1) {
        const int mv = mask[b * D1 + t];
        m_lds[t] = mv;
        out[(size_t)b * D1 + t] = (float)mv;
    }
    __syncthreads();
    for (int jj = 0; jj < 32; ++jj) {
        const int j = wave * 32 + jj;
        const int m = m_lds[j];
        float acc = 0.f;
#pragma unroll
        for (int c = 0; c < 16; ++c) {
            const int d = c * 64 + lane;
            acc = fmaf(w1[(size_t)d * D_FF + j * N_ELEM + m], x_lds[d], acc);
        }
#pragma unroll
        for (int off = 32; off; off >>= 1) acc += __shfl_down(acc, off);
        if (lane == 0) relu_lds[j] = fmaxf(acc, 0.f);
    }
    __syncthreads();
    const int dm0 = t * 4;
    const float4 bv = *(const float4*)(b2 + dm0);
    float a0 = bv.x, a1 = bv.y, a2 = bv.z, a3 = bv.w;
    for (int j = 0; j < D1; ++j) {
        const float r = relu_lds[j];
        if (r > 0.f) {
            const float4 wv = *(const float4*)(w2 + (size_t)(m_lds[j] * D1 + j) * D_MODEL + dm0);
            a0 = fmaf(r, wv.x, a0); a1 = fmaf(r, wv.y, a1);
            a2 = fmaf(r, wv.z, a2); a3 = fmaf(r, wv.w, a3);
        }
    }
    *(float4*)(out + (size_t)BATCH * D1 + (size_t)b * D_MODEL + dm0) =
        make_float4(a0, a1, a2, a3);
}

extern "C" void kernel_launch(void* const* d_in, const int* in_sizes, int n_in,
                              void* d_out, int out_size, void* d_ws, size_t ws_size,
                              hipStream_t stream) {
    const int*   mask = (const int*)d_in[0];
    const float* x    = (const float*)d_in[1];
    const float* w1   = (const float*)d_in[2];
    const float* w2   = (const float*)d_in[3];
    const float* b2   = (const float*)d_in[4];
    float* out = (float*)d_out;

    const size_t w1h_bytes  = (size_t)D_FF * D_MODEL * sizeof(u16);          // 16 MiB
    const size_t w2h_bytes  = (size_t)D_FF * D_MODEL * sizeof(u16);          // 16 MiB
    const size_t part_bytes = (size_t)NJT * BATCH * D_MODEL * sizeof(u16);   // 32 MiB

    if (ws_size >= w1h_bytes + w2h_bytes + part_bytes) {
        u16* w1h  = (u16*)d_ws;
        u16* w2h  = (u16*)((char*)d_ws + w1h_bytes);
        u16* part = (u16*)((char*)d_ws + w1h_bytes + w2h_bytes);
        const int cast_blocks = (D_FF * D_MODEL / 8) / 256;                  // 4096
        prep_weights<<<TW1_BLOCKS + cast_blocks, 256, 0, stream>>>(w1, w1h, w2, w2h);
        sparse_ff_jt<<<(BATCH / B_T) * NJT, 256, 0, stream>>>(mask, x, w1h, w2h, part);
        reduce_partials<<<BATCH, 256, 0, stream>>>(mask, b2, part, out);
    } else {
        sparse_ff_f32_raw<<<BATCH, 256, 0, stream>>>(mask, x, w1, w2, b2, out);
    }
}